// Round 1
// baseline (913.274 us; speedup 1.0000x reference)
//
#include <hip/hip_runtime.h>
#include <hip/hip_bf16.h>

// Problem constants
static constexpr int Bc   = 2;
static constexpr int Nc   = 512;
static constexpr int Mc   = 512;
static constexpr int D0c  = 1024;
static constexpr int Dc   = 100;   // embed dim
static constexpr int Hc   = 50;    // hidden channels
static constexpr int PADc = 3;     // (7-1)/2
static constexpr int SLAB  = 128;
static constexpr int SLABH = SLAB + 2*PADc; // 134
static constexpr int NSLAB = Nc / SLAB;     // 4
static constexpr long long NMc = (long long)Nc * Mc; // 262144

// ---------------------------------------------------------------------------
// k_embed: e = relu(x @ W_proj + b_proj) for both x0 (rows 0..1023) and x1.
// 8 rows/block, 256 threads; double accumulators (ref compared vs fp64 numpy).
// ---------------------------------------------------------------------------
__global__ __launch_bounds__(256) void k_embed(
    const float* __restrict__ x0, const float* __restrict__ x1,
    const float* __restrict__ Wp, const float* __restrict__ bp,
    float* __restrict__ e0, float* __restrict__ e1)
{
  __shared__ float xs[8][132];   // pad 128->132 to spread banks
  const int t    = threadIdx.x;
  const int rloc = t >> 5;        // 0..7
  const int ct   = t & 31;        // 0..31
  const int rg0  = blockIdx.x * 8;
  const int rg   = rg0 + rloc;
  const bool has2 = (ct < 18);    // cols 64+2ct..65+2ct cover 64..99

  double a00 = 0.0, a01 = 0.0, a10 = 0.0, a11 = 0.0;

  for (int kc = 0; kc < D0c; kc += 128) {
    { // stage 8x128 floats = 256 float4, one per thread
      const int rr = t >> 5;
      const int c4 = t & 31;
      const int rgs = rg0 + rr;
      const float* src = (rgs < Bc*Nc) ? (x0 + (size_t)rgs * D0c)
                                       : (x1 + (size_t)(rgs - Bc*Nc) * D0c);
      float4 v = *(const float4*)&src[kc + c4*4];
      *(float4*)&xs[rr][c4*4] = v;
    }
    __syncthreads();
    for (int k = 0; k < 128; ++k) {
      const float xv = xs[rloc][k];
      const int kg = kc + k;
      float2 w0 = *(const float2*)&Wp[(size_t)kg*Dc + 2*ct];
      a00 += (double)xv * (double)w0.x;
      a01 += (double)xv * (double)w0.y;
      if (has2) {
        float2 w1 = *(const float2*)&Wp[(size_t)kg*Dc + 64 + 2*ct];
        a10 += (double)xv * (double)w1.x;
        a11 += (double)xv * (double)w1.y;
      }
    }
    __syncthreads();
  }

  float* dst = (rg < Bc*Nc) ? (e0 + (size_t)rg*Dc) : (e1 + (size_t)(rg - Bc*Nc)*Dc);
  {
    float2 s0;
    s0.x = fmaxf((float)a00 + bp[2*ct],   0.f);
    s0.y = fmaxf((float)a01 + bp[2*ct+1], 0.f);
    *(float2*)&dst[2*ct] = s0;
    if (has2) {
      float2 s1;
      s1.x = fmaxf((float)a10 + bp[64+2*ct], 0.f);
      s1.y = fmaxf((float)a11 + bp[65+2*ct], 0.f);
      *(float2*)&dst[64+2*ct] = s1;
    }
  }
}

// ---------------------------------------------------------------------------
// k_hh: Hh[b,h,n,m] = relu( sum_d |e0-e1|*W_hid[d,h] + (e0*e1)*W_hid[D+d,h] + b_hid[h] )
// One slab of rows: local rows 0..133 map to global n = slab_n0 + lr.
// Block: 16x16 (n,m) tile, 320 threads = 5 waves; wave w owns h = 10w..10w+9;
// lane owns a 2x2 point patch -> acc[2][2][10].
// ---------------------------------------------------------------------------
__global__ __launch_bounds__(320, 4) void k_hh(
    const float* __restrict__ e0, const float* __restrict__ e1,
    const float* __restrict__ Whid, const float* __restrict__ bhid,
    float* __restrict__ hh, int slab_n0)
{
  __shared__ float Wl[200*50];     // 40 KB
  __shared__ float e0T[100*16];    // transposed [d][r]
  __shared__ float e1T[100*16];    // transposed [d][m]
  const int t   = threadIdx.x;
  const int b   = blockIdx.z;
  const int r0t = blockIdx.y * 16;
  const int m0t = blockIdx.x * 16;

  for (int i = t; i < 200*50; i += 320) Wl[i] = Whid[i];
  for (int i = t; i < 16*100; i += 320) {
    const int r = i / 100, d = i % 100;
    const int n = slab_n0 + r0t + r;
    e0T[d*16 + r] = (n >= 0 && n < Nc) ? e0[((size_t)(b*Nc + n))*Dc + d] : 0.f;
    const int m = m0t + r;
    e1T[d*16 + r] = e1[((size_t)(b*Mc + m))*Dc + d];
  }
  __syncthreads();

  const int wave = t >> 6;            // 0..4
  const int lane = t & 63;
  const int r0l  = 2 * (lane >> 3);   // 0,2,..,14
  const int m0l  = 2 * (lane & 7);    // 0,2,..,14
  const int hbase = wave * 10;

  float acc[2][2][10];
  #pragma unroll
  for (int i = 0; i < 2; ++i)
    #pragma unroll
    for (int j = 0; j < 2; ++j)
      #pragma unroll
      for (int k = 0; k < 10; ++k) acc[i][j][k] = 0.f;

  for (int d = 0; d < 100; ++d) {
    const float2 a0 = *(const float2*)&e0T[d*16 + r0l];
    const float2 a1 = *(const float2*)&e1T[d*16 + m0l];
    float wdv[10], wmv[10];
    #pragma unroll
    for (int k = 0; k < 5; ++k) {
      float2 td = *(const float2*)&Wl[d*50 + hbase + 2*k];
      wdv[2*k] = td.x; wdv[2*k+1] = td.y;
      float2 tm = *(const float2*)&Wl[(100+d)*50 + hbase + 2*k];
      wmv[2*k] = tm.x; wmv[2*k+1] = tm.y;
    }
    const float ev0[2] = {a0.x, a0.y};
    const float ev1[2] = {a1.x, a1.y};
    #pragma unroll
    for (int i = 0; i < 2; ++i) {
      #pragma unroll
      for (int j = 0; j < 2; ++j) {
        const float df = fabsf(ev0[i] - ev1[j]);
        const float pm = ev0[i] * ev1[j];
        #pragma unroll
        for (int k = 0; k < 10; ++k)
          acc[i][j][k] = fmaf(df, wdv[k], fmaf(pm, wmv[k], acc[i][j][k]));
      }
    }
  }

  #pragma unroll
  for (int k = 0; k < 10; ++k) {
    const int h = hbase + k;
    const float bh = bhid[h];
    #pragma unroll
    for (int i = 0; i < 2; ++i) {
      const int lr = r0t + r0l + i;
      const int n  = slab_n0 + lr;
      if (lr < SLABH && n >= 0 && n < Nc) {
        float2 v;
        v.x = fmaxf(acc[i][0][k] + bh, 0.f);
        v.y = fmaxf(acc[i][1][k] + bh, 0.f);
        *(float2*)&hh[(((size_t)(b*Hc + h))*SLABH + lr)*Mc + (m0t + m0l)] = v;
      }
    }
  }
}

// ---------------------------------------------------------------------------
// k_conv: 7x7x50->1 conv (cross-correlation, SAME) + sigmoid + positional
// weight + yhat store + double sum/sumsq block reduction (for mean/var).
// Tile: 32 rows x 16 cols, 256 threads, thread patch = 1 row x 2 cols.
// Per-h LDS plane 38x22 (double-buffered; reg-staged prefetch).
// ---------------------------------------------------------------------------
__global__ __launch_bounds__(256) void k_conv(
    const float* __restrict__ hh, const float* __restrict__ cw,
    const float* __restrict__ cb, const float* __restrict__ theta,
    const float* __restrict__ lam, float* __restrict__ yhat,
    double* __restrict__ gacc, int n_begin)
{
  __shared__ float cwl[Hc*49];          // 9.8 KB
  __shared__ float tile[2][38*26];      // pad 22->26 (even => 8B aligned b64)
  __shared__ double red[2][4];
  const int t  = threadIdx.x;
  const int b  = blockIdx.z;
  const int n0 = n_begin + blockIdx.y * 32;
  const int m0 = blockIdx.x * 16;

  for (int i = t; i < Hc*49; i += 256) cwl[i] = cw[i];

  const int rr = t >> 3;        // 0..31
  const int c0 = 2 * (t & 7);   // 0..14

  float stg[4];
  auto issue = [&](int h) {
    #pragma unroll
    for (int it = 0; it < 4; ++it) {
      const int idx = it*256 + t;
      float v = 0.f;
      if (idx < 38*22) {
        const int r = idx / 22, c = idx % 22;
        const int gn = n0 - 3 + r, gm = m0 - 3 + c;
        if (gn >= 0 && gn < Nc && gm >= 0 && gm < Mc)
          v = hh[(((size_t)(b*Hc + h))*SLABH + (gn - n_begin + 3))*Mc + gm];
      }
      stg[it] = v;
    }
  };
  auto commit = [&](int buf) {
    #pragma unroll
    for (int it = 0; it < 4; ++it) {
      const int idx = it*256 + t;
      if (idx < 38*22) tile[buf][(idx/22)*26 + (idx%22)] = stg[it];
    }
  };

  issue(0); commit(0);
  __syncthreads();

  float acc0 = 0.f, acc1 = 0.f;
  for (int h = 0; h < Hc; ++h) {
    if (h + 1 < Hc) issue(h + 1);           // prefetch next plane into regs
    const int buf = h & 1;
    #pragma unroll
    for (int dn = 0; dn < 7; ++dn) {
      const float* tp = &tile[buf][(rr+dn)*26 + c0];
      float w_[8];
      #pragma unroll
      for (int q = 0; q < 4; ++q) {
        float2 v2 = *(const float2*)&tp[2*q];
        w_[2*q] = v2.x; w_[2*q+1] = v2.y;
      }
      const float* cp = &cwl[h*49 + dn*7];
      #pragma unroll
      for (int dm = 0; dm < 7; ++dm) {
        const float wv = cp[dm];
        acc0 = fmaf(w_[dm],   wv, acc0);
        acc1 = fmaf(w_[dm+1], wv, acc1);
      }
    }
    __syncthreads();
    if (h + 1 < Hc) { commit((h+1) & 1); __syncthreads(); }
  }

  // epilogue: sigmoid, positional weight, store yhat, reduce sum/sumsq
  const float th  = theta[0];
  const float lm  = lam[0];
  const float cbv = cb[0];
  const int n = n0 + rr;
  const int m = m0 + c0;
  const float half1 = 0.5f * (float)(Nc + 1);     // 256.5
  const float inv   = 1.0f / half1;
  const float ti  = ((float)(n+1) - half1) * inv;
  const float av  = expf(-lm * ti * ti);
  const float tj0 = ((float)(m+1) - half1) * inv;
  const float tj1 = ((float)(m+2) - half1) * inv;
  const float bv0 = expf(-lm * tj0 * tj0);
  const float bv1 = expf(-lm * tj1 * tj1);
  const float s0 = 1.f / (1.f + expf(-(acc0 + cbv)));
  const float s1 = 1.f / (1.f + expf(-(acc1 + cbv)));
  const float y0 = s0 * ((1.f - th) * av * bv0 + th);
  const float y1 = s1 * ((1.f - th) * av * bv1 + th);
  float2 yv; yv.x = y0; yv.y = y1;
  *(float2*)&yhat[((size_t)(b*Nc + n))*Mc + m] = yv;

  double s  = (double)y0 + (double)y1;
  double ss = (double)y0*(double)y0 + (double)y1*(double)y1;
  for (int off = 32; off > 0; off >>= 1) {
    s  += __shfl_down(s,  off);
    ss += __shfl_down(ss, off);
  }
  const int wave = t >> 6, lane = t & 63;
  if (lane == 0) { red[0][wave] = s; red[1][wave] = ss; }
  __syncthreads();
  if (t == 0) {
    atomicAdd(&gacc[b*4 + 0], red[0][0] + red[0][1] + red[0][2] + red[0][3]);
    atomicAdd(&gacc[b*4 + 1], red[1][0] + red[1][1] + red[1][2] + red[1][3]);
  }
}

// ---------------------------------------------------------------------------
// k_q: Q = relu(yhat - mu - gamma*var); accumulate sum(Q) and count(Q>0).
// ---------------------------------------------------------------------------
__global__ __launch_bounds__(256) void k_q(
    const float* __restrict__ yhat, double* __restrict__ gacc,
    const float* __restrict__ gamma)
{
  const int tid = blockIdx.x * 256 + threadIdx.x;
  const int b = blockIdx.x >> 8;    // 256 blocks per batch
  const float4 y = ((const float4*)yhat)[tid];
  const double sum = gacc[b*4 + 0], ssq = gacc[b*4 + 1];
  const double mu  = sum / (double)NMc;
  const double var = (ssq - sum * mu) / ((double)NMc - 1.0);
  const double thr = mu + (double)gamma[0] * var;

  double sq = 0.0; int c = 0;
  double q;
  q = (double)y.x - thr; if (q > 0.0) { sq += q; ++c; }
  q = (double)y.y - thr; if (q > 0.0) { sq += q; ++c; }
  q = (double)y.z - thr; if (q > 0.0) { sq += q; ++c; }
  q = (double)y.w - thr; if (q > 0.0) { sq += q; ++c; }

  for (int off = 32; off > 0; off >>= 1) {
    sq += __shfl_down(sq, off);
    c  += __shfl_down(c,  off);
  }
  __shared__ double sr[4];
  __shared__ int    cr[4];
  const int wave = threadIdx.x >> 6, lane = threadIdx.x & 63;
  if (lane == 0) { sr[wave] = sq; cr[wave] = c; }
  __syncthreads();
  if (threadIdx.x == 0) {
    atomicAdd(&gacc[b*4 + 2], sr[0] + sr[1] + sr[2] + sr[3]);
    atomicAdd(&gacc[b*4 + 3], (double)(cr[0] + cr[1] + cr[2] + cr[3]));
  }
}

__global__ void k_out(const double* __restrict__ gacc, float* __restrict__ out)
{
  const int t = threadIdx.x;
  if (t < Bc) {
    const double phat = gacc[t*4 + 2] / (gacc[t*4 + 3] + 1.0);
    double v = 1.0 / (1.0 + exp(-20.0 * (phat - 0.5)));
    v = fmin(fmax(v, 0.0), 1.0);
    out[t] = (float)v;
  }
}

// ---------------------------------------------------------------------------
extern "C" void kernel_launch(void* const* d_in, const int* in_sizes, int n_in,
                              void* d_out, int out_size, void* d_ws, size_t ws_size,
                              hipStream_t stream)
{
  const float* x0 = (const float*)d_in[0];
  const float* x1 = (const float*)d_in[1];
  const float* Wp = (const float*)d_in[2];
  const float* bp = (const float*)d_in[3];
  const float* Wh = (const float*)d_in[4];
  const float* bh = (const float*)d_in[5];
  const float* cw = (const float*)d_in[6];
  const float* cb = (const float*)d_in[7];
  const float* th = (const float*)d_in[8];
  const float* lm = (const float*)d_in[9];
  const float* gm = (const float*)d_in[10];
  float* out = (float*)d_out;
  (void)in_sizes; (void)n_in; (void)out_size; (void)ws_size;

  char* ws = (char*)d_ws;
  float*  e0   = (float*)(ws);                                   // 409,600 B
  float*  e1   = (float*)(ws + 409600);                          // 409,600 B
  double* gacc = (double*)(ws + 819200);                         // 64 B
  float*  hh   = (float*)(ws + 1048576);                         // 27,443,200 B
  float*  yhat = (float*)(ws + 1048576 + 27443200);              // 2,097,152 B
  // total ws need: ~30.6 MB

  hipMemsetAsync(gacc, 0, 64, stream);
  k_embed<<<dim3(256), dim3(256), 0, stream>>>(x0, x1, Wp, bp, e0, e1);
  for (int s = 0; s < NSLAB; ++s) {
    const int slab_n0 = s * SLAB - PADc;
    k_hh  <<<dim3(32, 9, 2), dim3(320), 0, stream>>>(e0, e1, Wh, bh, hh, slab_n0);
    k_conv<<<dim3(32, 4, 2), dim3(256), 0, stream>>>(hh, cw, cb, th, lm, yhat, gacc, s * SLAB);
  }
  k_q  <<<dim3(512), dim3(256), 0, stream>>>(yhat, gacc, gm);
  k_out<<<dim3(1),   dim3(64),  0, stream>>>(gacc, out);
}

// Round 2
// 641.481 us; speedup vs baseline: 1.4237x; 1.4237x over previous
//
#include <hip/hip_runtime.h>
#include <hip/hip_bf16.h>

// Problem constants
static constexpr int Bc   = 2;
static constexpr int Nc   = 512;
static constexpr int Mc   = 512;
static constexpr int D0c  = 1024;
static constexpr int Dc   = 100;   // embed dim
static constexpr int Hc   = 50;    // hidden channels
static constexpr int PADc = 3;     // (7-1)/2
static constexpr int SLAB  = 128;
static constexpr int SLABH = SLAB + 2*PADc; // 134
static constexpr int NSLAB = Nc / SLAB;     // 4
static constexpr long long NMc = (long long)Nc * Mc; // 262144

// ---------------------------------------------------------------------------
// k_embed v2: e = relu(x @ W_proj + b_proj), fp32 accumulation.
// Block = 512 threads, 8 rows staged in LDS (32 KB). Thread t: col c=t&127
// (active c<100), quarter q=t>>7 owns rows 2q,2q+1. W column loads coalesced,
// unroll 8 -> 8 loads in flight; x via broadcast float4 LDS reads.
// Grid 256 blocks -> 8 waves/CU.
// ---------------------------------------------------------------------------
__global__ __launch_bounds__(512) void k_embed(
    const float* __restrict__ x0, const float* __restrict__ x1,
    const float* __restrict__ Wp, const float* __restrict__ bp,
    float* __restrict__ e0, float* __restrict__ e1)
{
  __shared__ float xs[8][1024];   // 32 KB
  const int t   = threadIdx.x;
  const int rg0 = blockIdx.x * 8;

  // stage 8 rows = 2048 float4, 4 per thread
  #pragma unroll
  for (int i = 0; i < 4; ++i) {
    const int idx = i*512 + t;       // 0..2047
    const int r   = idx >> 8;        // 256 float4 per row
    const int c4  = idx & 255;
    const int rgs = rg0 + r;
    const float* src = (rgs < Bc*Nc) ? (x0 + (size_t)rgs * D0c)
                                     : (x1 + (size_t)(rgs - Bc*Nc) * D0c);
    *(float4*)&xs[r][c4*4] = *(const float4*)&src[c4*4];
  }
  __syncthreads();

  const int c = t & 127;
  const int q = t >> 7;         // 0..3
  if (c < Dc) {
    const int row0 = q*2, row1 = q*2 + 1;
    float acc0 = 0.f, acc1 = 0.f;
    for (int k = 0; k < D0c; k += 8) {
      float w[8];
      #pragma unroll
      for (int u = 0; u < 8; ++u) w[u] = Wp[(k+u)*Dc + c];
      const float4 xa0 = *(const float4*)&xs[row0][k];
      const float4 xb0 = *(const float4*)&xs[row0][k+4];
      const float4 xa1 = *(const float4*)&xs[row1][k];
      const float4 xb1 = *(const float4*)&xs[row1][k+4];
      acc0 = fmaf(xa0.x, w[0], acc0); acc1 = fmaf(xa1.x, w[0], acc1);
      acc0 = fmaf(xa0.y, w[1], acc0); acc1 = fmaf(xa1.y, w[1], acc1);
      acc0 = fmaf(xa0.z, w[2], acc0); acc1 = fmaf(xa1.z, w[2], acc1);
      acc0 = fmaf(xa0.w, w[3], acc0); acc1 = fmaf(xa1.w, w[3], acc1);
      acc0 = fmaf(xb0.x, w[4], acc0); acc1 = fmaf(xb1.x, w[4], acc1);
      acc0 = fmaf(xb0.y, w[5], acc0); acc1 = fmaf(xb1.y, w[5], acc1);
      acc0 = fmaf(xb0.z, w[6], acc0); acc1 = fmaf(xb1.z, w[6], acc1);
      acc0 = fmaf(xb0.w, w[7], acc0); acc1 = fmaf(xb1.w, w[7], acc1);
    }
    const float bias = bp[c];
    {
      const int rg = rg0 + row0;
      const float v = fmaxf(acc0 + bias, 0.f);
      if (rg < Bc*Nc) e0[(size_t)rg*Dc + c] = v;
      else            e1[(size_t)(rg - Bc*Nc)*Dc + c] = v;
    }
    {
      const int rg = rg0 + row1;
      const float v = fmaxf(acc1 + bias, 0.f);
      if (rg < Bc*Nc) e0[(size_t)rg*Dc + c] = v;
      else            e1[(size_t)(rg - Bc*Nc)*Dc + c] = v;
    }
  }
}

// ---------------------------------------------------------------------------
// k_hh: Hh[b,h,n,m] = relu( sum_d |e0-e1|*W_hid[d,h] + (e0*e1)*W_hid[D+d,h] + b_hid[h] )
// One slab of rows: local rows 0..133 map to global n = slab_n0 + lr.
// Block: 16x16 (n,m) tile, 320 threads = 5 waves; wave w owns h = 10w..10w+9;
// lane owns a 2x2 point patch -> acc[2][2][10].
// ---------------------------------------------------------------------------
__global__ __launch_bounds__(320, 4) void k_hh(
    const float* __restrict__ e0, const float* __restrict__ e1,
    const float* __restrict__ Whid, const float* __restrict__ bhid,
    float* __restrict__ hh, int slab_n0)
{
  __shared__ float Wl[200*50];     // 40 KB
  __shared__ float e0T[100*16];    // transposed [d][r]
  __shared__ float e1T[100*16];    // transposed [d][m]
  const int t   = threadIdx.x;
  const int b   = blockIdx.z;
  const int r0t = blockIdx.y * 16;
  const int m0t = blockIdx.x * 16;

  for (int i = t; i < 200*50; i += 320) Wl[i] = Whid[i];
  for (int i = t; i < 16*100; i += 320) {
    const int r = i / 100, d = i % 100;
    const int n = slab_n0 + r0t + r;
    e0T[d*16 + r] = (n >= 0 && n < Nc) ? e0[((size_t)(b*Nc + n))*Dc + d] : 0.f;
    const int m = m0t + r;
    e1T[d*16 + r] = e1[((size_t)(b*Mc + m))*Dc + d];
  }
  __syncthreads();

  const int wave = t >> 6;            // 0..4
  const int lane = t & 63;
  const int r0l  = 2 * (lane >> 3);   // 0,2,..,14
  const int m0l  = 2 * (lane & 7);    // 0,2,..,14
  const int hbase = wave * 10;

  float acc[2][2][10];
  #pragma unroll
  for (int i = 0; i < 2; ++i)
    #pragma unroll
    for (int j = 0; j < 2; ++j)
      #pragma unroll
      for (int k = 0; k < 10; ++k) acc[i][j][k] = 0.f;

  for (int d = 0; d < 100; ++d) {
    const float2 a0 = *(const float2*)&e0T[d*16 + r0l];
    const float2 a1 = *(const float2*)&e1T[d*16 + m0l];
    float wdv[10], wmv[10];
    #pragma unroll
    for (int k = 0; k < 5; ++k) {
      float2 td = *(const float2*)&Wl[d*50 + hbase + 2*k];
      wdv[2*k] = td.x; wdv[2*k+1] = td.y;
      float2 tm = *(const float2*)&Wl[(100+d)*50 + hbase + 2*k];
      wmv[2*k] = tm.x; wmv[2*k+1] = tm.y;
    }
    const float ev0[2] = {a0.x, a0.y};
    const float ev1[2] = {a1.x, a1.y};
    #pragma unroll
    for (int i = 0; i < 2; ++i) {
      #pragma unroll
      for (int j = 0; j < 2; ++j) {
        const float df = fabsf(ev0[i] - ev1[j]);
        const float pm = ev0[i] * ev1[j];
        #pragma unroll
        for (int k = 0; k < 10; ++k)
          acc[i][j][k] = fmaf(df, wdv[k], fmaf(pm, wmv[k], acc[i][j][k]));
      }
    }
  }

  #pragma unroll
  for (int k = 0; k < 10; ++k) {
    const int h = hbase + k;
    const float bh = bhid[h];
    #pragma unroll
    for (int i = 0; i < 2; ++i) {
      const int lr = r0t + r0l + i;
      const int n  = slab_n0 + lr;
      if (lr < SLABH && n >= 0 && n < Nc) {
        float2 v;
        v.x = fmaxf(acc[i][0][k] + bh, 0.f);
        v.y = fmaxf(acc[i][1][k] + bh, 0.f);
        *(float2*)&hh[(((size_t)(b*Hc + h))*SLABH + lr)*Mc + (m0t + m0l)] = v;
      }
    }
  }
}

// ---------------------------------------------------------------------------
// k_conv: 7x7x50->1 conv (cross-correlation, SAME) + sigmoid + positional
// weight + yhat store + double sum/sumsq block reduction (for mean/var).
// Tile: 32 rows x 16 cols, 256 threads, thread patch = 1 row x 2 cols.
// Per-h LDS plane 38x22 (double-buffered; reg-staged prefetch).
// ---------------------------------------------------------------------------
__global__ __launch_bounds__(256) void k_conv(
    const float* __restrict__ hh, const float* __restrict__ cw,
    const float* __restrict__ cb, const float* __restrict__ theta,
    const float* __restrict__ lam, float* __restrict__ yhat,
    double* __restrict__ gacc, int n_begin)
{
  __shared__ float cwl[Hc*49];          // 9.8 KB
  __shared__ float tile[2][38*26];      // pad 22->26 (even => 8B aligned b64)
  __shared__ double red[2][4];
  const int t  = threadIdx.x;
  const int b  = blockIdx.z;
  const int n0 = n_begin + blockIdx.y * 32;
  const int m0 = blockIdx.x * 16;

  for (int i = t; i < Hc*49; i += 256) cwl[i] = cw[i];

  const int rr = t >> 3;        // 0..31
  const int c0 = 2 * (t & 7);   // 0..14

  float stg[4];
  auto issue = [&](int h) {
    #pragma unroll
    for (int it = 0; it < 4; ++it) {
      const int idx = it*256 + t;
      float v = 0.f;
      if (idx < 38*22) {
        const int r = idx / 22, c = idx % 22;
        const int gn = n0 - 3 + r, gm = m0 - 3 + c;
        if (gn >= 0 && gn < Nc && gm >= 0 && gm < Mc)
          v = hh[(((size_t)(b*Hc + h))*SLABH + (gn - n_begin + 3))*Mc + gm];
      }
      stg[it] = v;
    }
  };
  auto commit = [&](int buf) {
    #pragma unroll
    for (int it = 0; it < 4; ++it) {
      const int idx = it*256 + t;
      if (idx < 38*22) tile[buf][(idx/22)*26 + (idx%22)] = stg[it];
    }
  };

  issue(0); commit(0);
  __syncthreads();

  float acc0 = 0.f, acc1 = 0.f;
  for (int h = 0; h < Hc; ++h) {
    if (h + 1 < Hc) issue(h + 1);           // prefetch next plane into regs
    const int buf = h & 1;
    #pragma unroll
    for (int dn = 0; dn < 7; ++dn) {
      const float* tp = &tile[buf][(rr+dn)*26 + c0];
      float w_[8];
      #pragma unroll
      for (int q = 0; q < 4; ++q) {
        float2 v2 = *(const float2*)&tp[2*q];
        w_[2*q] = v2.x; w_[2*q+1] = v2.y;
      }
      const float* cp = &cwl[h*49 + dn*7];
      #pragma unroll
      for (int dm = 0; dm < 7; ++dm) {
        const float wv = cp[dm];
        acc0 = fmaf(w_[dm],   wv, acc0);
        acc1 = fmaf(w_[dm+1], wv, acc1);
      }
    }
    __syncthreads();
    if (h + 1 < Hc) { commit((h+1) & 1); __syncthreads(); }
  }

  // epilogue: sigmoid, positional weight, store yhat, reduce sum/sumsq
  const float th  = theta[0];
  const float lm  = lam[0];
  const float cbv = cb[0];
  const int n = n0 + rr;
  const int m = m0 + c0;
  const float half1 = 0.5f * (float)(Nc + 1);     // 256.5
  const float inv   = 1.0f / half1;
  const float ti  = ((float)(n+1) - half1) * inv;
  const float av  = expf(-lm * ti * ti);
  const float tj0 = ((float)(m+1) - half1) * inv;
  const float tj1 = ((float)(m+2) - half1) * inv;
  const float bv0 = expf(-lm * tj0 * tj0);
  const float bv1 = expf(-lm * tj1 * tj1);
  const float s0 = 1.f / (1.f + expf(-(acc0 + cbv)));
  const float s1 = 1.f / (1.f + expf(-(acc1 + cbv)));
  const float y0 = s0 * ((1.f - th) * av * bv0 + th);
  const float y1 = s1 * ((1.f - th) * av * bv1 + th);
  float2 yv; yv.x = y0; yv.y = y1;
  *(float2*)&yhat[((size_t)(b*Nc + n))*Mc + m] = yv;

  double s  = (double)y0 + (double)y1;
  double ss = (double)y0*(double)y0 + (double)y1*(double)y1;
  for (int off = 32; off > 0; off >>= 1) {
    s  += __shfl_down(s,  off);
    ss += __shfl_down(ss, off);
  }
  const int wave = t >> 6, lane = t & 63;
  if (lane == 0) { red[0][wave] = s; red[1][wave] = ss; }
  __syncthreads();
  if (t == 0) {
    atomicAdd(&gacc[b*4 + 0], red[0][0] + red[0][1] + red[0][2] + red[0][3]);
    atomicAdd(&gacc[b*4 + 1], red[1][0] + red[1][1] + red[1][2] + red[1][3]);
  }
}

// ---------------------------------------------------------------------------
// k_q: Q = relu(yhat - mu - gamma*var); accumulate sum(Q) and count(Q>0).
// ---------------------------------------------------------------------------
__global__ __launch_bounds__(256) void k_q(
    const float* __restrict__ yhat, double* __restrict__ gacc,
    const float* __restrict__ gamma)
{
  const int tid = blockIdx.x * 256 + threadIdx.x;
  const int b = blockIdx.x >> 8;    // 256 blocks per batch
  const float4 y = ((const float4*)yhat)[tid];
  const double sum = gacc[b*4 + 0], ssq = gacc[b*4 + 1];
  const double mu  = sum / (double)NMc;
  const double var = (ssq - sum * mu) / ((double)NMc - 1.0);
  const double thr = mu + (double)gamma[0] * var;

  double sq = 0.0; int c = 0;
  double q;
  q = (double)y.x - thr; if (q > 0.0) { sq += q; ++c; }
  q = (double)y.y - thr; if (q > 0.0) { sq += q; ++c; }
  q = (double)y.z - thr; if (q > 0.0) { sq += q; ++c; }
  q = (double)y.w - thr; if (q > 0.0) { sq += q; ++c; }

  for (int off = 32; off > 0; off >>= 1) {
    sq += __shfl_down(sq, off);
    c  += __shfl_down(c,  off);
  }
  __shared__ double sr[4];
  __shared__ int    cr[4];
  const int wave = threadIdx.x >> 6, lane = threadIdx.x & 63;
  if (lane == 0) { sr[wave] = sq; cr[wave] = c; }
  __syncthreads();
  if (threadIdx.x == 0) {
    atomicAdd(&gacc[b*4 + 2], sr[0] + sr[1] + sr[2] + sr[3]);
    atomicAdd(&gacc[b*4 + 3], (double)(cr[0] + cr[1] + cr[2] + cr[3]));
  }
}

__global__ void k_out(const double* __restrict__ gacc, float* __restrict__ out)
{
  const int t = threadIdx.x;
  if (t < Bc) {
    const double phat = gacc[t*4 + 2] / (gacc[t*4 + 3] + 1.0);
    double v = 1.0 / (1.0 + exp(-20.0 * (phat - 0.5)));
    v = fmin(fmax(v, 0.0), 1.0);
    out[t] = (float)v;
  }
}

// ---------------------------------------------------------------------------
extern "C" void kernel_launch(void* const* d_in, const int* in_sizes, int n_in,
                              void* d_out, int out_size, void* d_ws, size_t ws_size,
                              hipStream_t stream)
{
  const float* x0 = (const float*)d_in[0];
  const float* x1 = (const float*)d_in[1];
  const float* Wp = (const float*)d_in[2];
  const float* bp = (const float*)d_in[3];
  const float* Wh = (const float*)d_in[4];
  const float* bh = (const float*)d_in[5];
  const float* cw = (const float*)d_in[6];
  const float* cb = (const float*)d_in[7];
  const float* th = (const float*)d_in[8];
  const float* lm = (const float*)d_in[9];
  const float* gm = (const float*)d_in[10];
  float* out = (float*)d_out;
  (void)in_sizes; (void)n_in; (void)out_size; (void)ws_size;

  char* ws = (char*)d_ws;
  float*  e0   = (float*)(ws);                                   // 409,600 B
  float*  e1   = (float*)(ws + 409600);                          // 409,600 B
  double* gacc = (double*)(ws + 819200);                         // 64 B
  float*  hh   = (float*)(ws + 1048576);                         // 27,443,200 B
  float*  yhat = (float*)(ws + 1048576 + 27443200);              // 2,097,152 B
  // total ws need: ~30.6 MB

  hipMemsetAsync(gacc, 0, 64, stream);
  k_embed<<<dim3(256), dim3(512), 0, stream>>>(x0, x1, Wp, bp, e0, e1);
  for (int s = 0; s < NSLAB; ++s) {
    const int slab_n0 = s * SLAB - PADc;
    k_hh  <<<dim3(32, 9, 2), dim3(320), 0, stream>>>(e0, e1, Wh, bh, hh, slab_n0);
    k_conv<<<dim3(32, 4, 2), dim3(256), 0, stream>>>(hh, cw, cb, th, lm, yhat, gacc, s * SLAB);
  }
  k_q  <<<dim3(512), dim3(256), 0, stream>>>(yhat, gacc, gm);
  k_out<<<dim3(1),   dim3(64),  0, stream>>>(gacc, out);
}

// Round 3
// 343.929 us; speedup vs baseline: 2.6554x; 1.8652x over previous
//
#include <hip/hip_runtime.h>
#include <hip/hip_bf16.h>

// Problem constants
static constexpr int Bc   = 2;
static constexpr int Nc   = 512;
static constexpr int Mc   = 512;
static constexpr int D0c  = 1024;
static constexpr int Dc   = 100;   // embed dim
static constexpr int Hc   = 50;    // hidden channels
static constexpr long long NMc = (long long)Nc * Mc; // 262144

// ---------------------------------------------------------------------------
// k_embed: e = relu(x @ W_proj + b_proj), fp32 accumulation.
// Block = 512 threads, 8 rows staged in LDS (32 KB). Thread t: col c=t&127
// (active c<100), quarter q=t>>7 owns rows 2q,2q+1. W column loads coalesced,
// unroll 8 -> 8 loads in flight; x via broadcast float4 LDS reads.
// ---------------------------------------------------------------------------
__global__ __launch_bounds__(512) void k_embed(
    const float* __restrict__ x0, const float* __restrict__ x1,
    const float* __restrict__ Wp, const float* __restrict__ bp,
    float* __restrict__ e0, float* __restrict__ e1)
{
  __shared__ float xs[8][1024];   // 32 KB
  const int t   = threadIdx.x;
  const int rg0 = blockIdx.x * 8;

  #pragma unroll
  for (int i = 0; i < 4; ++i) {
    const int idx = i*512 + t;       // 0..2047
    const int r   = idx >> 8;        // 256 float4 per row
    const int c4  = idx & 255;
    const int rgs = rg0 + r;
    const float* src = (rgs < Bc*Nc) ? (x0 + (size_t)rgs * D0c)
                                     : (x1 + (size_t)(rgs - Bc*Nc) * D0c);
    *(float4*)&xs[r][c4*4] = *(const float4*)&src[c4*4];
  }
  __syncthreads();

  const int c = t & 127;
  const int q = t >> 7;         // 0..3
  if (c < Dc) {
    const int row0 = q*2, row1 = q*2 + 1;
    float acc0 = 0.f, acc1 = 0.f;
    for (int k = 0; k < D0c; k += 8) {
      float w[8];
      #pragma unroll
      for (int u = 0; u < 8; ++u) w[u] = Wp[(k+u)*Dc + c];
      const float4 xa0 = *(const float4*)&xs[row0][k];
      const float4 xb0 = *(const float4*)&xs[row0][k+4];
      const float4 xa1 = *(const float4*)&xs[row1][k];
      const float4 xb1 = *(const float4*)&xs[row1][k+4];
      acc0 = fmaf(xa0.x, w[0], acc0); acc1 = fmaf(xa1.x, w[0], acc1);
      acc0 = fmaf(xa0.y, w[1], acc0); acc1 = fmaf(xa1.y, w[1], acc1);
      acc0 = fmaf(xa0.z, w[2], acc0); acc1 = fmaf(xa1.z, w[2], acc1);
      acc0 = fmaf(xa0.w, w[3], acc0); acc1 = fmaf(xa1.w, w[3], acc1);
      acc0 = fmaf(xb0.x, w[4], acc0); acc1 = fmaf(xb1.x, w[4], acc1);
      acc0 = fmaf(xb0.y, w[5], acc0); acc1 = fmaf(xb1.y, w[5], acc1);
      acc0 = fmaf(xb0.z, w[6], acc0); acc1 = fmaf(xb1.z, w[6], acc1);
      acc0 = fmaf(xb0.w, w[7], acc0); acc1 = fmaf(xb1.w, w[7], acc1);
    }
    const float bias = bp[c];
    {
      const int rg = rg0 + row0;
      const float v = fmaxf(acc0 + bias, 0.f);
      if (rg < Bc*Nc) e0[(size_t)rg*Dc + c] = v;
      else            e1[(size_t)(rg - Bc*Nc)*Dc + c] = v;
    }
    {
      const int rg = rg0 + row1;
      const float v = fmaxf(acc1 + bias, 0.f);
      if (rg < Bc*Nc) e0[(size_t)rg*Dc + c] = v;
      else            e1[(size_t)(rg - Bc*Nc)*Dc + c] = v;
    }
  }
}

// ---------------------------------------------------------------------------
// k_hh v2: Hh[b,h,n,m] = relu(sum_d |e0-e1|*Wd + (e0*e1)*Wm + b_hid)
// W_hid read via SCALAR loads (wave-uniform index via readfirstlane) -> SMEM
// pipe, freeing the LDS pipe for the e-tiles. LDS = 12.8 KB (e-tiles only)
// -> ~6 blocks/CU. 320 thr = 5 waves; wave w owns h=10w..10w+9; lane owns a
// 2x2 (n,m) patch -> 40 accumulators.
// slabh = slab rows + 6 halo; local row lr -> global n = slab_n0 + lr.
// ---------------------------------------------------------------------------
__global__ __launch_bounds__(320) void k_hh(
    const float* __restrict__ e0, const float* __restrict__ e1,
    const float* __restrict__ Whid, const float* __restrict__ bhid,
    float* __restrict__ hh, int slab_n0, int slabh)
{
  __shared__ float e0T[100][16];
  __shared__ float e1T[100][16];
  const int t   = threadIdx.x;
  const int b   = blockIdx.z;
  const int r0t = blockIdx.y * 16;
  const int m0t = blockIdx.x * 16;

  // stage transposed e-tiles; consecutive t -> consecutive LDS addr (no conflicts)
  #pragma unroll
  for (int i = t; i < 1600; i += 320) {
    const int r = i & 15, d = i >> 4;
    const int n = slab_n0 + r0t + r;
    e0T[d][r] = ((unsigned)n < (unsigned)Nc) ? e0[((size_t)(b*Nc + n))*Dc + d] : 0.f;
    e1T[d][r] = e1[((size_t)(b*Mc + m0t + r))*Dc + d];
  }
  __syncthreads();

  const int lane  = t & 63;
  const int hbase = __builtin_amdgcn_readfirstlane((t >> 6) * 10);
  const int r0l   = 2 * (lane >> 3);   // 0,2,..,14
  const int m0l   = 2 * (lane & 7);    // 0,2,..,14

  float acc[2][2][10];
  #pragma unroll
  for (int i = 0; i < 2; ++i)
    #pragma unroll
    for (int j = 0; j < 2; ++j)
      #pragma unroll
      for (int k = 0; k < 10; ++k) acc[i][j][k] = 0.f;

  const float* __restrict__ wdp = Whid + hbase;
  const float* __restrict__ wmp = Whid + 100*Hc + hbase;

  #pragma unroll 2
  for (int d = 0; d < 100; ++d) {
    const float2 a0 = *(const float2*)&e0T[d][r0l];
    const float2 a1 = *(const float2*)&e1T[d][m0l];
    const float ev0[2] = {a0.x, a0.y};
    const float ev1[2] = {a1.x, a1.y};
    #pragma unroll
    for (int i = 0; i < 2; ++i) {
      #pragma unroll
      for (int j = 0; j < 2; ++j) {
        const float df = fabsf(ev0[i] - ev1[j]);
        const float pm = ev0[i] * ev1[j];
        #pragma unroll
        for (int k = 0; k < 10; ++k)
          acc[i][j][k] = fmaf(df, wdp[d*Hc + k], fmaf(pm, wmp[d*Hc + k], acc[i][j][k]));
      }
    }
  }

  #pragma unroll
  for (int k = 0; k < 10; ++k) {
    const int h = hbase + k;
    const float bh = bhid[h];
    #pragma unroll
    for (int i = 0; i < 2; ++i) {
      const int lr = r0t + r0l + i;
      const int n  = slab_n0 + lr;
      if (lr < slabh && (unsigned)n < (unsigned)Nc) {
        float2 v;
        v.x = fmaxf(acc[i][0][k] + bh, 0.f);
        v.y = fmaxf(acc[i][1][k] + bh, 0.f);
        *(float2*)&hh[(((size_t)(b*Hc + h))*slabh + lr)*Mc + (m0t + m0l)] = v;
      }
    }
  }
}

// ---------------------------------------------------------------------------
// k_conv v2: 7x7x50->1 conv + sigmoid + positional weight + yhat store +
// sum/sumsq reduction. Tile 32n x 32m, 256 threads, thread = 1 row x 4 cols.
// Per-h LDS plane [38][40] (stride 40, float4-aligned), double-buffered with
// reg-staged prefetch. Conv weights via scalar loads (wave-uniform).
// ---------------------------------------------------------------------------
__global__ __launch_bounds__(256) void k_conv(
    const float* __restrict__ hh, const float* __restrict__ cw,
    const float* __restrict__ cb, const float* __restrict__ theta,
    const float* __restrict__ lam, float* __restrict__ yhat,
    double* __restrict__ gacc, int n_begin, int slabh)
{
  __shared__ float tile[2][38*40];
  __shared__ double red[2][4];
  const int t  = threadIdx.x;
  const int b  = blockIdx.z;
  const int n0 = n_begin + blockIdx.y * 32;
  const int m0 = blockIdx.x * 32;

  const int rr = t >> 3;        // 0..31
  const int c0 = 4 * (t & 7);   // 0..28

  float stg[6];
  auto issue = [&](int h) {
    #pragma unroll
    for (int it = 0; it < 6; ++it) {
      const int idx = it*256 + t;
      float v = 0.f;
      if (idx < 38*38) {
        const int r = idx / 38, c = idx - r*38;
        const int gn = n0 - 3 + r, gm = m0 - 3 + c;
        if ((unsigned)gn < (unsigned)Nc && (unsigned)gm < (unsigned)Mc)
          v = hh[(((size_t)(b*Hc + h))*slabh + (gn - n_begin + 3))*Mc + gm];
      }
      stg[it] = v;
    }
  };
  auto commit = [&](int buf) {
    #pragma unroll
    for (int it = 0; it < 6; ++it) {
      const int idx = it*256 + t;
      if (idx < 38*38) {
        const int r = idx / 38, c = idx - r*38;
        tile[buf][r*40 + c] = stg[it];
      }
    }
  };

  issue(0); commit(0);
  __syncthreads();

  float acc0 = 0.f, acc1 = 0.f, acc2 = 0.f, acc3 = 0.f;
  for (int h = 0; h < Hc; ++h) {
    if (h + 1 < Hc) issue(h + 1);
    const int buf = h & 1;
    const float* __restrict__ cp = cw + h*49;
    #pragma unroll
    for (int dn = 0; dn < 7; ++dn) {
      const float* tp = &tile[buf][(rr+dn)*40 + c0];
      const float4 wa = *(const float4*)tp;
      const float4 wb = *(const float4*)(tp+4);
      const float2 wc = *(const float2*)(tp+8);
      const float w_[10] = {wa.x,wa.y,wa.z,wa.w, wb.x,wb.y,wb.z,wb.w, wc.x,wc.y};
      #pragma unroll
      for (int dm = 0; dm < 7; ++dm) {
        const float wv = cp[dn*7 + dm];       // wave-uniform -> s_load
        acc0 = fmaf(w_[dm],   wv, acc0);
        acc1 = fmaf(w_[dm+1], wv, acc1);
        acc2 = fmaf(w_[dm+2], wv, acc2);
        acc3 = fmaf(w_[dm+3], wv, acc3);
      }
    }
    __syncthreads();
    if (h + 1 < Hc) { commit((h+1) & 1); __syncthreads(); }
  }

  // epilogue
  const float th  = theta[0];
  const float lm  = lam[0];
  const float cbv = cb[0];
  const int n = n0 + rr;
  const int m = m0 + c0;
  const float half1 = 0.5f * (float)(Nc + 1);     // 256.5
  const float inv   = 1.0f / half1;
  const float ti  = ((float)(n+1) - half1) * inv;
  const float av  = expf(-lm * ti * ti);
  float y[4];
  double s = 0.0, ss = 0.0;
  const float a_[4] = {acc0, acc1, acc2, acc3};
  #pragma unroll
  for (int j = 0; j < 4; ++j) {
    const float tj = ((float)(m+1+j) - half1) * inv;
    const float bv = expf(-lm * tj * tj);
    const float sg = 1.f / (1.f + expf(-(a_[j] + cbv)));
    y[j] = sg * ((1.f - th) * av * bv + th);
    s  += (double)y[j];
    ss += (double)y[j] * (double)y[j];
  }
  float4 yv; yv.x = y[0]; yv.y = y[1]; yv.z = y[2]; yv.w = y[3];
  *(float4*)&yhat[((size_t)(b*Nc + n))*Mc + m] = yv;

  for (int off = 32; off > 0; off >>= 1) {
    s  += __shfl_down(s,  off);
    ss += __shfl_down(ss, off);
  }
  const int wave = t >> 6, lane = t & 63;
  if (lane == 0) { red[0][wave] = s; red[1][wave] = ss; }
  __syncthreads();
  if (t == 0) {
    atomicAdd(&gacc[b*4 + 0], red[0][0] + red[0][1] + red[0][2] + red[0][3]);
    atomicAdd(&gacc[b*4 + 1], red[1][0] + red[1][1] + red[1][2] + red[1][3]);
  }
}

// ---------------------------------------------------------------------------
// k_q: Q = relu(yhat - mu - gamma*var); accumulate sum(Q) and count(Q>0).
// ---------------------------------------------------------------------------
__global__ __launch_bounds__(256) void k_q(
    const float* __restrict__ yhat, double* __restrict__ gacc,
    const float* __restrict__ gamma)
{
  const int tid = blockIdx.x * 256 + threadIdx.x;
  const int b = blockIdx.x >> 8;    // 256 blocks per batch
  const float4 y = ((const float4*)yhat)[tid];
  const double sum = gacc[b*4 + 0], ssq = gacc[b*4 + 1];
  const double mu  = sum / (double)NMc;
  const double var = (ssq - sum * mu) / ((double)NMc - 1.0);
  const double thr = mu + (double)gamma[0] * var;

  double sq = 0.0; int c = 0;
  double q;
  q = (double)y.x - thr; if (q > 0.0) { sq += q; ++c; }
  q = (double)y.y - thr; if (q > 0.0) { sq += q; ++c; }
  q = (double)y.z - thr; if (q > 0.0) { sq += q; ++c; }
  q = (double)y.w - thr; if (q > 0.0) { sq += q; ++c; }

  for (int off = 32; off > 0; off >>= 1) {
    sq += __shfl_down(sq, off);
    c  += __shfl_down(c,  off);
  }
  __shared__ double sr[4];
  __shared__ int    cr[4];
  const int wave = threadIdx.x >> 6, lane = threadIdx.x & 63;
  if (lane == 0) { sr[wave] = sq; cr[wave] = c; }
  __syncthreads();
  if (threadIdx.x == 0) {
    atomicAdd(&gacc[b*4 + 2], sr[0] + sr[1] + sr[2] + sr[3]);
    atomicAdd(&gacc[b*4 + 3], (double)(cr[0] + cr[1] + cr[2] + cr[3]));
  }
}

__global__ void k_out(const double* __restrict__ gacc, float* __restrict__ out)
{
  const int t = threadIdx.x;
  if (t < Bc) {
    const double phat = gacc[t*4 + 2] / (gacc[t*4 + 3] + 1.0);
    double v = 1.0 / (1.0 + exp(-20.0 * (phat - 0.5)));
    v = fmin(fmax(v, 0.0), 1.0);
    out[t] = (float)v;
  }
}

// ---------------------------------------------------------------------------
extern "C" void kernel_launch(void* const* d_in, const int* in_sizes, int n_in,
                              void* d_out, int out_size, void* d_ws, size_t ws_size,
                              hipStream_t stream)
{
  const float* x0 = (const float*)d_in[0];
  const float* x1 = (const float*)d_in[1];
  const float* Wp = (const float*)d_in[2];
  const float* bp = (const float*)d_in[3];
  const float* Wh = (const float*)d_in[4];
  const float* bh = (const float*)d_in[5];
  const float* cw = (const float*)d_in[6];
  const float* cb = (const float*)d_in[7];
  const float* th = (const float*)d_in[8];
  const float* lm = (const float*)d_in[9];
  const float* gm = (const float*)d_in[10];
  float* out = (float*)d_out;
  (void)in_sizes; (void)n_in; (void)out_size;

  // adaptive slabbing: hh buffer = slabh*204800 bytes; pick largest that fits
  int slabrows, nslab;
  if      (ws_size >= (size_t)109232128) { slabrows = 512; nslab = 1; }
  else if (ws_size >= (size_t)56803328)  { slabrows = 256; nslab = 2; }
  else                                    { slabrows = 128; nslab = 4; }
  const int slabh = slabrows + 6;
  const size_t hh_bytes = (size_t)slabh * 204800;  // 2*50*slabh*512*4

  char* ws = (char*)d_ws;
  float*  e0   = (float*)(ws);                           // 409,600 B
  float*  e1   = (float*)(ws + 409600);                  // 409,600 B
  double* gacc = (double*)(ws + 819200);                 // 64 B
  float*  hh   = (float*)(ws + 1048576);
  float*  yhat = (float*)(ws + 1048576 + hh_bytes);      // 2,097,152 B

  hipMemsetAsync(gacc, 0, 64, stream);
  k_embed<<<dim3(256), dim3(512), 0, stream>>>(x0, x1, Wp, bp, e0, e1);
  for (int s = 0; s < nslab; ++s) {
    const int n_begin = s * slabrows;
    k_hh  <<<dim3(32, (slabh + 15) / 16, 2), dim3(320), 0, stream>>>(
        e0, e1, Wh, bh, hh, n_begin - 3, slabh);
    k_conv<<<dim3(16, slabrows / 32, 2), dim3(256), 0, stream>>>(
        hh, cw, cb, th, lm, yhat, gacc, n_begin, slabh);
  }
  k_q  <<<dim3(512), dim3(256), 0, stream>>>(yhat, gacc, gm);
  k_out<<<dim3(1),   dim3(64),  0, stream>>>(gacc, out);
}

// Round 4
// 302.486 us; speedup vs baseline: 3.0192x; 1.1370x over previous
//
#include <hip/hip_runtime.h>
#include <hip/hip_bf16.h>

// Problem constants
static constexpr int Bc   = 2;
static constexpr int Nc   = 512;
static constexpr int Mc   = 512;
static constexpr int D0c  = 1024;
static constexpr int Dc   = 100;   // embed dim
static constexpr int Hc   = 50;    // hidden channels
static constexpr long long NMc = (long long)Nc * Mc; // 262144

typedef __attribute__((ext_vector_type(8))) short short8v;
typedef __attribute__((ext_vector_type(4))) float f32x4;

// ---------------------------------------------------------------------------
// k_embed: e = relu(x @ W_proj + b_proj), fp32 accumulation. (unchanged)
// ---------------------------------------------------------------------------
__global__ __launch_bounds__(512) void k_embed(
    const float* __restrict__ x0, const float* __restrict__ x1,
    const float* __restrict__ Wp, const float* __restrict__ bp,
    float* __restrict__ e0, float* __restrict__ e1)
{
  __shared__ float xs[8][1024];   // 32 KB
  const int t   = threadIdx.x;
  const int rg0 = blockIdx.x * 8;

  #pragma unroll
  for (int i = 0; i < 4; ++i) {
    const int idx = i*512 + t;       // 0..2047
    const int r   = idx >> 8;        // 256 float4 per row
    const int c4  = idx & 255;
    const int rgs = rg0 + r;
    const float* src = (rgs < Bc*Nc) ? (x0 + (size_t)rgs * D0c)
                                     : (x1 + (size_t)(rgs - Bc*Nc) * D0c);
    *(float4*)&xs[r][c4*4] = *(const float4*)&src[c4*4];
  }
  __syncthreads();

  const int c = t & 127;
  const int q = t >> 7;         // 0..3
  if (c < Dc) {
    const int row0 = q*2, row1 = q*2 + 1;
    float acc0 = 0.f, acc1 = 0.f;
    for (int k = 0; k < D0c; k += 8) {
      float w[8];
      #pragma unroll
      for (int u = 0; u < 8; ++u) w[u] = Wp[(k+u)*Dc + c];
      const float4 xa0 = *(const float4*)&xs[row0][k];
      const float4 xb0 = *(const float4*)&xs[row0][k+4];
      const float4 xa1 = *(const float4*)&xs[row1][k];
      const float4 xb1 = *(const float4*)&xs[row1][k+4];
      acc0 = fmaf(xa0.x, w[0], acc0); acc1 = fmaf(xa1.x, w[0], acc1);
      acc0 = fmaf(xa0.y, w[1], acc0); acc1 = fmaf(xa1.y, w[1], acc1);
      acc0 = fmaf(xa0.z, w[2], acc0); acc1 = fmaf(xa1.z, w[2], acc1);
      acc0 = fmaf(xa0.w, w[3], acc0); acc1 = fmaf(xa1.w, w[3], acc1);
      acc0 = fmaf(xb0.x, w[4], acc0); acc1 = fmaf(xb1.x, w[4], acc1);
      acc0 = fmaf(xb0.y, w[5], acc0); acc1 = fmaf(xb1.y, w[5], acc1);
      acc0 = fmaf(xb0.z, w[6], acc0); acc1 = fmaf(xb1.z, w[6], acc1);
      acc0 = fmaf(xb0.w, w[7], acc0); acc1 = fmaf(xb1.w, w[7], acc1);
    }
    const float bias = bp[c];
    {
      const int rg = rg0 + row0;
      const float v = fmaxf(acc0 + bias, 0.f);
      if (rg < Bc*Nc) e0[(size_t)rg*Dc + c] = v;
      else            e1[(size_t)(rg - Bc*Nc)*Dc + c] = v;
    }
    {
      const int rg = rg0 + row1;
      const float v = fmaxf(acc1 + bias, 0.f);
      if (rg < Bc*Nc) e0[(size_t)rg*Dc + c] = v;
      else            e1[(size_t)(rg - Bc*Nc)*Dc + c] = v;
    }
  }
}

// ---------------------------------------------------------------------------
// k_wsplit: precompute split-bf16 B-fragments of W' (interleaved diff/mul
// weights), in OUR (lane,elem)->k convention so A and B agree (k-permutation
// invariance makes the HW's internal k-order irrelevant).
// frag fi = ((s*4 + ht)*2 + hl): s=k-step(7), ht=h-tile(4), hl=hi/lo.
// lane l: col h = ht*16 + (l&15); elems j: p=j>>2 (0=diff,1=mul), q=j&3,
// d = s*16 + (l>>4)*4 + q. Truncation split: hi = trunc_bf16(w), lo =
// trunc_bf16(w - hi).
// ---------------------------------------------------------------------------
__global__ __launch_bounds__(64) void k_wsplit(
    const float* __restrict__ Whid, uint4* __restrict__ wsplit)
{
  const int fi = blockIdx.x;          // 0..55
  const int s  = fi >> 3;
  const int ht = (fi >> 1) & 3;
  const int hl = fi & 1;
  const int lane = threadIdx.x;       // 0..63
  const int h_loc = lane & 15, g = lane >> 4;
  const int h = ht*16 + h_loc;
  uint dw[4] = {0u,0u,0u,0u};
  #pragma unroll
  for (int j = 0; j < 8; ++j) {
    const int p = j >> 2, q = j & 3;
    const int d = s*16 + g*4 + q;
    float wv = (h < Hc && d < Dc) ? Whid[(size_t)(p*Dc + d)*Hc + h] : 0.f;
    const uint bits = __float_as_uint(wv);
    const uint hi_bits = bits & 0xffff0000u;
    uint e16;
    if (hl == 0) e16 = hi_bits >> 16;
    else {
      const float lo = wv - __uint_as_float(hi_bits);
      e16 = __float_as_uint(lo) >> 16;
    }
    dw[j >> 1] |= e16 << (16 * (j & 1));
  }
  uint4 v; v.x = dw[0]; v.y = dw[1]; v.z = dw[2]; v.w = dw[3];
  wsplit[fi*64 + lane] = v;
}

// ---------------------------------------------------------------------------
// k_hh v3 (MFMA): Hh[b,h,n,m] = relu(sum_d |e0-e1|*Wd + (e0*e1)*Wm + b_hid)
// GEMM view: per block, fixed n; A rows = 16 m's; K = 224 (7 steps x 32,
// interleaved diff/mul, zero-padded d>=100); B cols = 64 h (padded from 50).
// Split-bf16: 3 MFMAs per (A,B) tile: Ahi*Bhi + Alo*Bhi + Ahi*Blo.
// Block 256 thr = 4 waves: wave w: m-tile (w>>1), h-half (w&1, 2 h-tiles).
// C layout (verified m89/m91): col=lane&15, row=(lane>>4)*4+reg.
// Transpose C through LDS for coalesced [h][n][m] stores.
// ---------------------------------------------------------------------------
__global__ __launch_bounds__(256) void k_hh(
    const float* __restrict__ e0, const float* __restrict__ e1,
    const uint4* __restrict__ wsplit, const float* __restrict__ bhid,
    float* __restrict__ hh, int slab_n0, int slabh)
{
  const int b  = blockIdx.z;
  const int lr = blockIdx.y;
  const int n  = slab_n0 + lr;
  if ((unsigned)n >= (unsigned)Nc) return;

  __shared__ float e1T[32][112];
  __shared__ float e0s[112];
  __shared__ float biasl[64];
  __shared__ float ldsC[4][2][16][17];

  const int t   = threadIdx.x;
  const int m0b = blockIdx.x * 32;

  for (int i = t; i < 32*112; i += 256) {
    const int row = i / 112, col = i - row*112;
    e1T[row][col] = (col < Dc) ? e1[((size_t)(b*Mc + m0b + row))*Dc + col] : 0.f;
  }
  if (t < 112) e0s[t] = (t < Dc) ? e0[((size_t)(b*Nc + n))*Dc + t] : 0.f;
  if (t >= 128 && t < 192) { const int h = t - 128; biasl[h] = (h < Hc) ? bhid[h] : 0.f; }
  __syncthreads();

  const int w = t >> 6, lane = t & 63;
  const int cl = lane & 15, g = lane >> 4;   // cl: A-row (m) in loop, C-col (h) in epilogue
  const int mt = w >> 1;
  const int hhalf = w & 1;

  f32x4 c0 = {0.f,0.f,0.f,0.f}, c1 = {0.f,0.f,0.f,0.f};

  union U { uint4 u; short8v v; };

  for (int s = 0; s < 7; ++s) {
    const int d0 = s*16 + g*4;
    const float4 E1 = *(const float4*)&e1T[mt*16 + cl][d0];
    const float4 E0 = *(const float4*)&e0s[d0];

    const float df0 = fabsf(E0.x - E1.x), df1 = fabsf(E0.y - E1.y),
                df2 = fabsf(E0.z - E1.z), df3 = fabsf(E0.w - E1.w);
    const float pm0 = E0.x*E1.x, pm1 = E0.y*E1.y,
                pm2 = E0.z*E1.z, pm3 = E0.w*E1.w;

    // truncation split; pack pairs (elem j even -> low16)
    #define PK(a,bq) ((__float_as_uint(bq) & 0xffff0000u) | (__float_as_uint(a) >> 16))
    #define LO(x) ((x) - __uint_as_float(__float_as_uint(x) & 0xffff0000u))
    U ahi, alo;
    ahi.u.x = PK(df0, df1); ahi.u.y = PK(df2, df3);
    ahi.u.z = PK(pm0, pm1); ahi.u.w = PK(pm2, pm3);
    const float l0 = LO(df0), l1 = LO(df1), l2 = LO(df2), l3 = LO(df3);
    const float l4 = LO(pm0), l5 = LO(pm1), l6 = LO(pm2), l7 = LO(pm3);
    alo.u.x = PK(l0, l1); alo.u.y = PK(l2, l3);
    alo.u.z = PK(l4, l5); alo.u.w = PK(l6, l7);
    #undef PK
    #undef LO

    const int ht0 = hhalf*2, ht1 = hhalf*2 + 1;
    U whi0, wlo0, whi1, wlo1;
    whi0.u = wsplit[((s*4 + ht0)*2 + 0)*64 + lane];
    wlo0.u = wsplit[((s*4 + ht0)*2 + 1)*64 + lane];
    whi1.u = wsplit[((s*4 + ht1)*2 + 0)*64 + lane];
    wlo1.u = wsplit[((s*4 + ht1)*2 + 1)*64 + lane];

    c0 = __builtin_amdgcn_mfma_f32_16x16x32_bf16(ahi.v, whi0.v, c0, 0, 0, 0);
    c0 = __builtin_amdgcn_mfma_f32_16x16x32_bf16(alo.v, whi0.v, c0, 0, 0, 0);
    c0 = __builtin_amdgcn_mfma_f32_16x16x32_bf16(ahi.v, wlo0.v, c0, 0, 0, 0);
    c1 = __builtin_amdgcn_mfma_f32_16x16x32_bf16(ahi.v, whi1.v, c1, 0, 0, 0);
    c1 = __builtin_amdgcn_mfma_f32_16x16x32_bf16(alo.v, whi1.v, c1, 0, 0, 0);
    c1 = __builtin_amdgcn_mfma_f32_16x16x32_bf16(ahi.v, wlo1.v, c1, 0, 0, 0);
  }

  // C -> LDS (transpose): C col = h (cl), row = m (g*4+r)
  #pragma unroll
  for (int r = 0; r < 4; ++r) {
    ldsC[w][0][cl][g*4 + r] = c0[r];
    ldsC[w][1][cl][g*4 + r] = c1[r];
  }
  // wave-private region, wave-synchronous: no barrier needed

  // coalesced stores: pass handles 4 h-rows x 16 m
  #pragma unroll
  for (int pass = 0; pass < 8; ++pass) {
    const int row   = pass*4 + g;        // 0..31 over 2 tiles
    const int tile  = row >> 4, hl2 = row & 15;
    const int h     = (hhalf*2 + tile)*16 + hl2;
    if (h < Hc) {
      float v = ldsC[w][tile][hl2][cl] + biasl[h];
      v = fmaxf(v, 0.f);
      hh[(((size_t)(b*Hc + h))*slabh + lr)*Mc + (m0b + mt*16 + cl)] = v;
    }
  }
}

// ---------------------------------------------------------------------------
// k_conv: 7x7x50->1 conv + sigmoid + positional weight + yhat store +
// sum/sumsq reduction. (unchanged)
// ---------------------------------------------------------------------------
__global__ __launch_bounds__(256) void k_conv(
    const float* __restrict__ hh, const float* __restrict__ cw,
    const float* __restrict__ cb, const float* __restrict__ theta,
    const float* __restrict__ lam, float* __restrict__ yhat,
    double* __restrict__ gacc, int n_begin, int slabh)
{
  __shared__ float tile[2][38*40];
  __shared__ double red[2][4];
  const int t  = threadIdx.x;
  const int b  = blockIdx.z;
  const int n0 = n_begin + blockIdx.y * 32;
  const int m0 = blockIdx.x * 32;

  const int rr = t >> 3;        // 0..31
  const int c0 = 4 * (t & 7);   // 0..28

  float stg[6];
  auto issue = [&](int h) {
    #pragma unroll
    for (int it = 0; it < 6; ++it) {
      const int idx = it*256 + t;
      float v = 0.f;
      if (idx < 38*38) {
        const int r = idx / 38, c = idx - r*38;
        const int gn = n0 - 3 + r, gm = m0 - 3 + c;
        if ((unsigned)gn < (unsigned)Nc && (unsigned)gm < (unsigned)Mc)
          v = hh[(((size_t)(b*Hc + h))*slabh + (gn - n_begin + 3))*Mc + gm];
      }
      stg[it] = v;
    }
  };
  auto commit = [&](int buf) {
    #pragma unroll
    for (int it = 0; it < 6; ++it) {
      const int idx = it*256 + t;
      if (idx < 38*38) {
        const int r = idx / 38, c = idx - r*38;
        tile[buf][r*40 + c] = stg[it];
      }
    }
  };

  issue(0); commit(0);
  __syncthreads();

  float acc0 = 0.f, acc1 = 0.f, acc2 = 0.f, acc3 = 0.f;
  for (int h = 0; h < Hc; ++h) {
    if (h + 1 < Hc) issue(h + 1);
    const int buf = h & 1;
    const float* __restrict__ cp = cw + h*49;
    #pragma unroll
    for (int dn = 0; dn < 7; ++dn) {
      const float* tp = &tile[buf][(rr+dn)*40 + c0];
      const float4 wa = *(const float4*)tp;
      const float4 wb = *(const float4*)(tp+4);
      const float2 wc = *(const float2*)(tp+8);
      const float w_[10] = {wa.x,wa.y,wa.z,wa.w, wb.x,wb.y,wb.z,wb.w, wc.x,wc.y};
      #pragma unroll
      for (int dm = 0; dm < 7; ++dm) {
        const float wv = cp[dn*7 + dm];       // wave-uniform -> s_load
        acc0 = fmaf(w_[dm],   wv, acc0);
        acc1 = fmaf(w_[dm+1], wv, acc1);
        acc2 = fmaf(w_[dm+2], wv, acc2);
        acc3 = fmaf(w_[dm+3], wv, acc3);
      }
    }
    __syncthreads();
    if (h + 1 < Hc) { commit((h+1) & 1); __syncthreads(); }
  }

  // epilogue
  const float th  = theta[0];
  const float lm  = lam[0];
  const float cbv = cb[0];
  const int n = n0 + rr;
  const int m = m0 + c0;
  const float half1 = 0.5f * (float)(Nc + 1);     // 256.5
  const float inv   = 1.0f / half1;
  const float ti  = ((float)(n+1) - half1) * inv;
  const float av  = expf(-lm * ti * ti);
  float y[4];
  double s = 0.0, ss = 0.0;
  const float a_[4] = {acc0, acc1, acc2, acc3};
  #pragma unroll
  for (int j = 0; j < 4; ++j) {
    const float tj = ((float)(m+1+j) - half1) * inv;
    const float bv = expf(-lm * tj * tj);
    const float sg = 1.f / (1.f + expf(-(a_[j] + cbv)));
    y[j] = sg * ((1.f - th) * av * bv + th);
    s  += (double)y[j];
    ss += (double)y[j] * (double)y[j];
  }
  float4 yv; yv.x = y[0]; yv.y = y[1]; yv.z = y[2]; yv.w = y[3];
  *(float4*)&yhat[((size_t)(b*Nc + n))*Mc + m] = yv;

  for (int off = 32; off > 0; off >>= 1) {
    s  += __shfl_down(s,  off);
    ss += __shfl_down(ss, off);
  }
  const int wave = t >> 6, lane = t & 63;
  if (lane == 0) { red[0][wave] = s; red[1][wave] = ss; }
  __syncthreads();
  if (t == 0) {
    atomicAdd(&gacc[b*4 + 0], red[0][0] + red[0][1] + red[0][2] + red[0][3]);
    atomicAdd(&gacc[b*4 + 1], red[1][0] + red[1][1] + red[1][2] + red[1][3]);
  }
}

// ---------------------------------------------------------------------------
// k_q: Q = relu(yhat - mu - gamma*var); accumulate sum(Q) and count(Q>0).
// ---------------------------------------------------------------------------
__global__ __launch_bounds__(256) void k_q(
    const float* __restrict__ yhat, double* __restrict__ gacc,
    const float* __restrict__ gamma)
{
  const int tid = blockIdx.x * 256 + threadIdx.x;
  const int b = blockIdx.x >> 8;    // 256 blocks per batch
  const float4 y = ((const float4*)yhat)[tid];
  const double sum = gacc[b*4 + 0], ssq = gacc[b*4 + 1];
  const double mu  = sum / (double)NMc;
  const double var = (ssq - sum * mu) / ((double)NMc - 1.0);
  const double thr = mu + (double)gamma[0] * var;

  double sq = 0.0; int c = 0;
  double q;
  q = (double)y.x - thr; if (q > 0.0) { sq += q; ++c; }
  q = (double)y.y - thr; if (q > 0.0) { sq += q; ++c; }
  q = (double)y.z - thr; if (q > 0.0) { sq += q; ++c; }
  q = (double)y.w - thr; if (q > 0.0) { sq += q; ++c; }

  for (int off = 32; off > 0; off >>= 1) {
    sq += __shfl_down(sq, off);
    c  += __shfl_down(c,  off);
  }
  __shared__ double sr[4];
  __shared__ int    cr[4];
  const int wave = threadIdx.x >> 6, lane = threadIdx.x & 63;
  if (lane == 0) { sr[wave] = sq; cr[wave] = c; }
  __syncthreads();
  if (threadIdx.x == 0) {
    atomicAdd(&gacc[b*4 + 2], sr[0] + sr[1] + sr[2] + sr[3]);
    atomicAdd(&gacc[b*4 + 3], (double)(cr[0] + cr[1] + cr[2] + cr[3]));
  }
}

__global__ void k_out(const double* __restrict__ gacc, float* __restrict__ out)
{
  const int t = threadIdx.x;
  if (t < Bc) {
    const double phat = gacc[t*4 + 2] / (gacc[t*4 + 3] + 1.0);
    double v = 1.0 / (1.0 + exp(-20.0 * (phat - 0.5)));
    v = fmin(fmax(v, 0.0), 1.0);
    out[t] = (float)v;
  }
}

// ---------------------------------------------------------------------------
extern "C" void kernel_launch(void* const* d_in, const int* in_sizes, int n_in,
                              void* d_out, int out_size, void* d_ws, size_t ws_size,
                              hipStream_t stream)
{
  const float* x0 = (const float*)d_in[0];
  const float* x1 = (const float*)d_in[1];
  const float* Wp = (const float*)d_in[2];
  const float* bp = (const float*)d_in[3];
  const float* Wh = (const float*)d_in[4];
  const float* bh = (const float*)d_in[5];
  const float* cw = (const float*)d_in[6];
  const float* cb = (const float*)d_in[7];
  const float* th = (const float*)d_in[8];
  const float* lm = (const float*)d_in[9];
  const float* gm = (const float*)d_in[10];
  float* out = (float*)d_out;
  (void)in_sizes; (void)n_in; (void)out_size;

  // adaptive slabbing: hh buffer = slabh*204800 bytes; pick largest that fits
  int slabrows, nslab;
  if      (ws_size >= (size_t)109232128) { slabrows = 512; nslab = 1; }
  else if (ws_size >= (size_t)56803328)  { slabrows = 256; nslab = 2; }
  else                                    { slabrows = 128; nslab = 4; }
  const int slabh = slabrows + 6;
  const size_t hh_bytes = (size_t)slabh * 204800;  // 2*50*slabh*512*4

  char* ws = (char*)d_ws;
  float*  e0   = (float*)(ws);                           // 409,600 B
  float*  e1   = (float*)(ws + 409600);                  // 409,600 B
  double* gacc = (double*)(ws + 819200);                 // 64 B
  uint4*  wsp  = (uint4*)(ws + 884736);                  // 57,344 B
  float*  hh   = (float*)(ws + 1048576);
  float*  yhat = (float*)(ws + 1048576 + hh_bytes);      // 2,097,152 B

  hipMemsetAsync(gacc, 0, 64, stream);
  k_wsplit<<<dim3(56), dim3(64), 0, stream>>>(Wh, wsp);
  k_embed<<<dim3(256), dim3(512), 0, stream>>>(x0, x1, Wp, bp, e0, e1);
  for (int s = 0; s < nslab; ++s) {
    const int n_begin = s * slabrows;
    k_hh  <<<dim3(16, slabh, 2), dim3(256), 0, stream>>>(
        e0, e1, wsp, bh, hh, n_begin - 3, slabh);
    k_conv<<<dim3(16, slabrows / 32, 2), dim3(256), 0, stream>>>(
        hh, cw, cb, th, lm, yhat, gacc, n_begin, slabh);
  }
  k_q  <<<dim3(512), dim3(256), 0, stream>>>(yhat, gacc, gm);
  k_out<<<dim3(1),   dim3(64),  0, stream>>>(gacc, out);
}

// Round 6
// 283.740 us; speedup vs baseline: 3.2187x; 1.0661x over previous
//
#include <hip/hip_runtime.h>
#include <hip/hip_bf16.h>

// Problem constants
static constexpr int Bc   = 2;
static constexpr int Nc   = 512;
static constexpr int Mc   = 512;
static constexpr int D0c  = 1024;
static constexpr int Dc   = 100;   // embed dim
static constexpr int Hc   = 50;    // hidden channels
static constexpr long long NMc = (long long)Nc * Mc; // 262144

typedef __attribute__((ext_vector_type(8))) short short8v;
typedef __attribute__((ext_vector_type(4))) float f32x4;

// trunc-bf16 pack: low16 = a[31:16], high16 = b[31:16]  (1 v_perm_b32)
__device__ __forceinline__ unsigned pk_hi(float a, float b) {
  return __builtin_amdgcn_perm(__float_as_uint(b), __float_as_uint(a), 0x07060302u);
}
__device__ __forceinline__ float trunc16(float x) {
  return __uint_as_float(__float_as_uint(x) & 0xffff0000u);
}

// ---------------------------------------------------------------------------
// k_embed: e = relu(x @ W_proj + b_proj), fp32 accumulation. (unchanged)
// ---------------------------------------------------------------------------
__global__ __launch_bounds__(512) void k_embed(
    const float* __restrict__ x0, const float* __restrict__ x1,
    const float* __restrict__ Wp, const float* __restrict__ bp,
    float* __restrict__ e0, float* __restrict__ e1)
{
  __shared__ float xs[8][1024];   // 32 KB
  const int t   = threadIdx.x;
  const int rg0 = blockIdx.x * 8;

  #pragma unroll
  for (int i = 0; i < 4; ++i) {
    const int idx = i*512 + t;       // 0..2047
    const int r   = idx >> 8;        // 256 float4 per row
    const int c4  = idx & 255;
    const int rgs = rg0 + r;
    const float* src = (rgs < Bc*Nc) ? (x0 + (size_t)rgs * D0c)
                                     : (x1 + (size_t)(rgs - Bc*Nc) * D0c);
    *(float4*)&xs[r][c4*4] = *(const float4*)&src[c4*4];
  }
  __syncthreads();

  const int c = t & 127;
  const int q = t >> 7;         // 0..3
  if (c < Dc) {
    const int row0 = q*2, row1 = q*2 + 1;
    float acc0 = 0.f, acc1 = 0.f;
    for (int k = 0; k < D0c; k += 8) {
      float w[8];
      #pragma unroll
      for (int u = 0; u < 8; ++u) w[u] = Wp[(k+u)*Dc + c];
      const float4 xa0 = *(const float4*)&xs[row0][k];
      const float4 xb0 = *(const float4*)&xs[row0][k+4];
      const float4 xa1 = *(const float4*)&xs[row1][k];
      const float4 xb1 = *(const float4*)&xs[row1][k+4];
      acc0 = fmaf(xa0.x, w[0], acc0); acc1 = fmaf(xa1.x, w[0], acc1);
      acc0 = fmaf(xa0.y, w[1], acc0); acc1 = fmaf(xa1.y, w[1], acc1);
      acc0 = fmaf(xa0.z, w[2], acc0); acc1 = fmaf(xa1.z, w[2], acc1);
      acc0 = fmaf(xa0.w, w[3], acc0); acc1 = fmaf(xa1.w, w[3], acc1);
      acc0 = fmaf(xb0.x, w[4], acc0); acc1 = fmaf(xb1.x, w[4], acc1);
      acc0 = fmaf(xb0.y, w[5], acc0); acc1 = fmaf(xb1.y, w[5], acc1);
      acc0 = fmaf(xb0.z, w[6], acc0); acc1 = fmaf(xb1.z, w[6], acc1);
      acc0 = fmaf(xb0.w, w[7], acc0); acc1 = fmaf(xb1.w, w[7], acc1);
    }
    const float bias = bp[c];
    {
      const int rg = rg0 + row0;
      const float v = fmaxf(acc0 + bias, 0.f);
      if (rg < Bc*Nc) e0[(size_t)rg*Dc + c] = v;
      else            e1[(size_t)(rg - Bc*Nc)*Dc + c] = v;
    }
    {
      const int rg = rg0 + row1;
      const float v = fmaxf(acc1 + bias, 0.f);
      if (rg < Bc*Nc) e0[(size_t)rg*Dc + c] = v;
      else            e1[(size_t)(rg - Bc*Nc)*Dc + c] = v;
    }
  }
}

// ---------------------------------------------------------------------------
// k_wsplit: split-bf16 B-fragments of W' in our (lane,elem)->k convention.
// (unchanged from round 4 -- convention PROVEN by absmax 0.0)
// ---------------------------------------------------------------------------
__global__ __launch_bounds__(64) void k_wsplit(
    const float* __restrict__ Whid, uint4* __restrict__ wsplit)
{
  const int fi = blockIdx.x;          // 0..55
  const int s  = fi >> 3;
  const int ht = (fi >> 1) & 3;
  const int hl = fi & 1;
  const int lane = threadIdx.x;       // 0..63
  const int h_loc = lane & 15, g = lane >> 4;
  const int h = ht*16 + h_loc;
  uint dw[4] = {0u,0u,0u,0u};
  #pragma unroll
  for (int j = 0; j < 8; ++j) {
    const int p = j >> 2, q = j & 3;
    const int d = s*16 + g*4 + q;
    float wv = (h < Hc && d < Dc) ? Whid[(size_t)(p*Dc + d)*Hc + h] : 0.f;
    const uint bits = __float_as_uint(wv);
    const uint hi_bits = bits & 0xffff0000u;
    uint e16;
    if (hl == 0) e16 = hi_bits >> 16;
    else {
      const float lo = wv - __uint_as_float(hi_bits);
      e16 = __float_as_uint(lo) >> 16;
    }
    dw[j >> 1] |= e16 << (16 * (j & 1));
  }
  uint4 v; v.x = dw[0]; v.y = dw[1]; v.z = dw[2]; v.w = dw[3];
  wsplit[fi*64 + lane] = v;
}

// ---------------------------------------------------------------------------
// k_hh v4 (MFMA): block = 2 n-rows x 32 m. 4 waves; wave w = (n-local w>>1,
// m-tile w&1) and ALL 4 h-tiles (no A duplication). A-frags built with
// v_perm packs (trunc split, same numerics as v3). e1T stride 116 (2-way
// bank aliasing only). Same k_wsplit fragments; C layout col=lane&15 (h),
// row=(lane>>4)*4+reg (m). Per-tile wave-sync LDS transpose for coalesced
// stores.
// ---------------------------------------------------------------------------
__global__ __launch_bounds__(256, 4) void k_hh(
    const float* __restrict__ e0, const float* __restrict__ e1,
    const uint4* __restrict__ wsplit, const float* __restrict__ bhid,
    float* __restrict__ hh, int slab_n0, int slabh)
{
  const int b   = blockIdx.z;
  const int lr0 = blockIdx.y * 2;
  const int n0base = slab_n0 + lr0;
  if (n0base + 1 < 0 || n0base >= Nc) return;   // both rows out of range

  __shared__ float e1T[32][116];    // 14848 B (stride 116: 2-way only)
  __shared__ float e0s[2][112];     // 896 B
  __shared__ float biasl[64];       // 256 B
  __shared__ float ldsT[4][16][17]; // 4352 B

  const int t   = threadIdx.x;
  const int m0b = blockIdx.x * 32;

  { // stage e1T rows m0b..m0b+31, cols 0..111 (division-free)
    const int row = t >> 3;          // 0..31
    const int cb  = (t & 7) * 4;     // 0..28
    const float* src = e1 + (size_t)(b*Mc + m0b + row) * Dc;
    #pragma unroll
    for (int pass = 0; pass < 4; ++pass) {
      const int col = cb + pass*32;
      if (col < 112) {
        float4 v = {0.f,0.f,0.f,0.f};
        if (col < Dc) v = *(const float4*)&src[col];
        *(float4*)&e1T[row][col] = v;
      }
    }
  }
  { // stage e0s (2 rows, zero-padded / zero if n invalid)
    const int nl2 = t >> 7, col = t & 127;
    if (col < 112) {
      const int n = n0base + nl2;
      float v = 0.f;
      if ((unsigned)n < (unsigned)Nc && col < Dc)
        v = e0[(size_t)(b*Nc + n)*Dc + col];
      e0s[nl2][col] = v;
    }
  }
  if (t < 64) biasl[t] = (t < Hc) ? bhid[t] : 0.f;
  __syncthreads();

  const int w = t >> 6, lane = t & 63;
  const int cl = lane & 15, g = lane >> 4;
  const int nl   = w >> 1;             // n-local
  const int mrow = (w & 1) * 16 + cl;  // e1T row = m-local

  f32x4 acc0 = {0.f,0.f,0.f,0.f}, acc1 = {0.f,0.f,0.f,0.f};
  f32x4 acc2 = {0.f,0.f,0.f,0.f}, acc3 = {0.f,0.f,0.f,0.f};

  union U { uint4 u; short8v v; };
  const uint4* __restrict__ wq = wsplit + lane;

  #pragma unroll
  for (int s = 0; s < 7; ++s) {
    const int d0 = s*16 + g*4;
    const float4 E1 = *(const float4*)&e1T[mrow][d0];
    const float4 E0 = *(const float4*)&e0s[nl][d0];

    const float df0 = fabsf(E0.x - E1.x), df1 = fabsf(E0.y - E1.y),
                df2 = fabsf(E0.z - E1.z), df3 = fabsf(E0.w - E1.w);
    const float pm0 = E0.x*E1.x, pm1 = E0.y*E1.y,
                pm2 = E0.z*E1.z, pm3 = E0.w*E1.w;

    U ahi, alo;
    ahi.u.x = pk_hi(df0, df1); ahi.u.y = pk_hi(df2, df3);
    ahi.u.z = pk_hi(pm0, pm1); ahi.u.w = pk_hi(pm2, pm3);
    alo.u.x = pk_hi(df0 - trunc16(df0), df1 - trunc16(df1));
    alo.u.y = pk_hi(df2 - trunc16(df2), df3 - trunc16(df3));
    alo.u.z = pk_hi(pm0 - trunc16(pm0), pm1 - trunc16(pm1));
    alo.u.w = pk_hi(pm2 - trunc16(pm2), pm3 - trunc16(pm3));

    #pragma unroll
    for (int ht = 0; ht < 4; ++ht) {
      U whi, wlo;
      whi.u = wq[((s*4 + ht)*2 + 0)*64];
      wlo.u = wq[((s*4 + ht)*2 + 1)*64];
      f32x4* ac = (ht == 0) ? &acc0 : (ht == 1) ? &acc1 : (ht == 2) ? &acc2 : &acc3;
      *ac = __builtin_amdgcn_mfma_f32_16x16x32_bf16(ahi.v, whi.v, *ac, 0, 0, 0);
      *ac = __builtin_amdgcn_mfma_f32_16x16x32_bf16(alo.v, whi.v, *ac, 0, 0, 0);
      *ac = __builtin_amdgcn_mfma_f32_16x16x32_bf16(ahi.v, wlo.v, *ac, 0, 0, 0);
    }
  }

  // epilogue: per-tile wave-sync transpose through LDS, coalesced stores
  const int n = n0base + nl;
  const bool nvalid = (unsigned)n < (unsigned)Nc;
  const int S = slabh * Mc;                 // scalar row stride (h)
  float* hhp = hh + ((size_t)b*Hc)*S + (size_t)(lr0 + nl)*Mc
                  + (m0b + (w & 1)*16 + cl) + (size_t)g*S;

  const f32x4 accs[4] = {acc0, acc1, acc2, acc3};
  #pragma unroll
  for (int ht = 0; ht < 4; ++ht) {
    #pragma unroll
    for (int r = 0; r < 4; ++r) ldsT[w][cl][g*4 + r] = accs[ht][r];
    // same-wave LDS: compiler-inserted lgkmcnt wait orders write->read
    #pragma unroll
    for (int p = 0; p < 4; ++p) {
      const int hl2 = p*4 + g;
      const int h = ht*16 + hl2;
      if (h < Hc && nvalid) {
        const float v = fmaxf(ldsT[w][hl2][cl] + biasl[h], 0.f);
        hhp[(size_t)((ht*16 + p*4) * S)] = v;
      }
    }
  }
}

// ---------------------------------------------------------------------------
// k_conv: 7x7x50->1 conv + sigmoid + positional weight + yhat store +
// sum/sumsq reduction. Single barrier per h (commit into the other buffer).
// ---------------------------------------------------------------------------
__global__ __launch_bounds__(256) void k_conv(
    const float* __restrict__ hh, const float* __restrict__ cw,
    const float* __restrict__ cb, const float* __restrict__ theta,
    const float* __restrict__ lam, float* __restrict__ yhat,
    double* __restrict__ gacc, int n_begin, int slabh)
{
  __shared__ float tile[2][38*40];
  __shared__ double red[2][4];
  const int t  = threadIdx.x;
  const int b  = blockIdx.z;
  const int n0 = n_begin + blockIdx.y * 32;
  const int m0 = blockIdx.x * 32;

  const int rr = t >> 3;        // 0..31
  const int c0 = 4 * (t & 7);   // 0..28

  float stg[6];
  auto issue = [&](int h) {
    #pragma unroll
    for (int it = 0; it < 6; ++it) {
      const int idx = it*256 + t;
      float v = 0.f;
      if (idx < 38*38) {
        const int r = idx / 38, c = idx - r*38;
        const int gn = n0 - 3 + r, gm = m0 - 3 + c;
        if ((unsigned)gn < (unsigned)Nc && (unsigned)gm < (unsigned)Mc)
          v = hh[(((size_t)(b*Hc + h))*slabh + (gn - n_begin + 3))*Mc + gm];
      }
      stg[it] = v;
    }
  };
  auto commit = [&](int buf) {
    #pragma unroll
    for (int it = 0; it < 6; ++it) {
      const int idx = it*256 + t;
      if (idx < 38*38) {
        const int r = idx / 38, c = idx - r*38;
        tile[buf][r*40 + c] = stg[it];
      }
    }
  };

  issue(0); commit(0);
  __syncthreads();

  float acc0 = 0.f, acc1 = 0.f, acc2 = 0.f, acc3 = 0.f;
  for (int h = 0; h < Hc; ++h) {
    if (h + 1 < Hc) issue(h + 1);
    const int buf = h & 1;
    const float* __restrict__ cp = cw + h*49;
    #pragma unroll
    for (int dn = 0; dn < 7; ++dn) {
      const float* tp = &tile[buf][(rr+dn)*40 + c0];
      const float4 wa = *(const float4*)tp;
      const float4 wb = *(const float4*)(tp+4);
      const float2 wc = *(const float2*)(tp+8);
      const float w_[10] = {wa.x,wa.y,wa.z,wa.w, wb.x,wb.y,wb.z,wb.w, wc.x,wc.y};
      #pragma unroll
      for (int dm = 0; dm < 7; ++dm) {
        const float wv = cp[dn*7 + dm];       // wave-uniform -> s_load
        acc0 = fmaf(w_[dm],   wv, acc0);
        acc1 = fmaf(w_[dm+1], wv, acc1);
        acc2 = fmaf(w_[dm+2], wv, acc2);
        acc3 = fmaf(w_[dm+3], wv, acc3);
      }
    }
    // commit writes the OTHER buffer: no reader conflict -> one barrier per h
    if (h + 1 < Hc) { commit((h+1) & 1); __syncthreads(); }
  }

  // epilogue
  const float th  = theta[0];
  const float lm  = lam[0];
  const float cbv = cb[0];
  const int n = n0 + rr;
  const int m = m0 + c0;
  const float half1 = 0.5f * (float)(Nc + 1);     // 256.5
  const float inv   = 1.0f / half1;
  const float ti  = ((float)(n+1) - half1) * inv;
  const float av  = expf(-lm * ti * ti);
  float y[4];
  double s = 0.0, ss = 0.0;
  const float a_[4] = {acc0, acc1, acc2, acc3};
  #pragma unroll
  for (int j = 0; j < 4; ++j) {
    const float tj = ((float)(m+1+j) - half1) * inv;
    const float bv = expf(-lm * tj * tj);
    const float sg = 1.f / (1.f + expf(-(a_[j] + cbv)));
    y[j] = sg * ((1.f - th) * av * bv + th);
    s  += (double)y[j];
    ss += (double)y[j] * (double)y[j];
  }
  float4 yv; yv.x = y[0]; yv.y = y[1]; yv.z = y[2]; yv.w = y[3];
  *(float4*)&yhat[((size_t)(b*Nc + n))*Mc + m] = yv;

  for (int off = 32; off > 0; off >>= 1) {
    s  += __shfl_down(s,  off);
    ss += __shfl_down(ss, off);
  }
  const int wave = t >> 6, lane = t & 63;
  if (lane == 0) { red[0][wave] = s; red[1][wave] = ss; }
  __syncthreads();
  if (t == 0) {
    atomicAdd(&gacc[b*4 + 0], red[0][0] + red[0][1] + red[0][2] + red[0][3]);
    atomicAdd(&gacc[b*4 + 1], red[1][0] + red[1][1] + red[1][2] + red[1][3]);
  }
}

// ---------------------------------------------------------------------------
// k_q: Q = relu(yhat - mu - gamma*var); accumulate sum(Q) and count(Q>0).
// ---------------------------------------------------------------------------
__global__ __launch_bounds__(256) void k_q(
    const float* __restrict__ yhat, double* __restrict__ gacc,
    const float* __restrict__ gamma)
{
  const int tid = blockIdx.x * 256 + threadIdx.x;
  const int b = blockIdx.x >> 8;    // 256 blocks per batch
  const float4 y = ((const float4*)yhat)[tid];
  const double sum = gacc[b*4 + 0], ssq = gacc[b*4 + 1];
  const double mu  = sum / (double)NMc;
  const double var = (ssq - sum * mu) / ((double)NMc - 1.0);
  const double thr = mu + (double)gamma[0] * var;

  double sq = 0.0; int c = 0;
  double q;
  q = (double)y.x - thr; if (q > 0.0) { sq += q; ++c; }
  q = (double)y.y - thr; if (q > 0.0) { sq += q; ++c; }
  q = (double)y.z - thr; if (q > 0.0) { sq += q; ++c; }
  q = (double)y.w - thr; if (q > 0.0) { sq += q; ++c; }

  for (int off = 32; off > 0; off >>= 1) {
    sq += __shfl_down(sq, off);
    c  += __shfl_down(c,  off);
  }
  __shared__ double sr[4];
  __shared__ int    cr[4];
  const int wave = threadIdx.x >> 6, lane = threadIdx.x & 63;
  if (lane == 0) { sr[wave] = sq; cr[wave] = c; }
  __syncthreads();
  if (threadIdx.x == 0) {
    atomicAdd(&gacc[b*4 + 2], sr[0] + sr[1] + sr[2] + sr[3]);
    atomicAdd(&gacc[b*4 + 3], (double)(cr[0] + cr[1] + cr[2] + cr[3]));
  }
}

__global__ void k_out(const double* __restrict__ gacc, float* __restrict__ out)
{
  const int t = threadIdx.x;
  if (t < Bc) {
    const double phat = gacc[t*4 + 2] / (gacc[t*4 + 3] + 1.0);
    double v = 1.0 / (1.0 + exp(-20.0 * (phat - 0.5)));
    v = fmin(fmax(v, 0.0), 1.0);
    out[t] = (float)v;
  }
}

// ---------------------------------------------------------------------------
extern "C" void kernel_launch(void* const* d_in, const int* in_sizes, int n_in,
                              void* d_out, int out_size, void* d_ws, size_t ws_size,
                              hipStream_t stream)
{
  const float* x0 = (const float*)d_in[0];
  const float* x1 = (const float*)d_in[1];
  const float* Wp = (const float*)d_in[2];
  const float* bp = (const float*)d_in[3];
  const float* Wh = (const float*)d_in[4];
  const float* bh = (const float*)d_in[5];
  const float* cw = (const float*)d_in[6];
  const float* cb = (const float*)d_in[7];
  const float* th = (const float*)d_in[8];
  const float* lm = (const float*)d_in[9];
  const float* gm = (const float*)d_in[10];
  float* out = (float*)d_out;
  (void)in_sizes; (void)n_in; (void)out_size;

  // adaptive slabbing: hh buffer = slabh*204800 bytes; pick largest that fits
  int slabrows, nslab;
  if      (ws_size >= (size_t)109232128) { slabrows = 512; nslab = 1; }
  else if (ws_size >= (size_t)56803328)  { slabrows = 256; nslab = 2; }
  else                                    { slabrows = 128; nslab = 4; }
  const int slabh = slabrows + 6;
  const size_t hh_bytes = (size_t)slabh * 204800;  // 2*50*slabh*512*4

  char* ws = (char*)d_ws;
  float*  e0   = (float*)(ws);                           // 409,600 B
  float*  e1   = (float*)(ws + 409600);                  // 409,600 B
  double* gacc = (double*)(ws + 819200);                 // 64 B
  uint4*  wsp  = (uint4*)(ws + 884736);                  // 57,344 B
  float*  hh   = (float*)(ws + 1048576);
  float*  yhat = (float*)(ws + 1048576 + hh_bytes);      // 2,097,152 B

  hipMemsetAsync(gacc, 0, 64, stream);
  k_wsplit<<<dim3(56), dim3(64), 0, stream>>>(Wh, wsp);
  k_embed<<<dim3(256), dim3(512), 0, stream>>>(x0, x1, Wp, bp, e0, e1);
  for (int s = 0; s < nslab; ++s) {
    const int n_begin = s * slabrows;
    k_hh  <<<dim3(16, slabh/2, 2), dim3(256), 0, stream>>>(
        e0, e1, wsp, bh, hh, n_begin - 3, slabh);
    k_conv<<<dim3(16, slabrows / 32, 2), dim3(256), 0, stream>>>(
        hh, cw, cb, th, lm, yhat, gacc, n_begin, slabh);
  }
  k_q  <<<dim3(512), dim3(256), 0, stream>>>(yhat, gacc, gm);
  k_out<<<dim3(1),   dim3(64),  0, stream>>>(gacc, out);
}